// Round 15
// baseline (26.478 us; speedup 1.0000x reference)
//
#include <hip/hip_runtime.h>
#include <math.h>

#define B 8
#define C 4
#define H 512
#define W 512
#define SEL 1
#define BIGI 1024       // H + W
#define NPIX (B*H*W)
#define CH 64           // rows per chunk
#define RC 8            // chunks per column
#define TC 32           // columns per block
#define NSEG 16         // segments per chunk
#define LL 4            // rows per thread (CH/NSEG)
#define CINF 3000       // "infinite" carry
#define G 8             // rows per row_fused block
#define NRU (B*H/G)     // 512 row blocks
#define LOG2E 1.4426950408889634f
#define SCALE_F 1048576.0f          // 2^20 fixed-point for deterministic integer atomics
#define INV_SCALE (1.0 / 1048576.0)

// ---------------- local (per-chunk) vertical EDT, both polarities ----------------
// gpkT layout: [b][i/4][j][4] u16, value = (g<<1)|fg.  Block 0 also re-arms parts/cnt.
__global__ __launch_bounds__(512) void col_two_level(const float* __restrict__ ytrue,
                                                     unsigned short* __restrict__ gpkT,
                                                     unsigned* __restrict__ sumsD,
                                                     unsigned* __restrict__ sumsU,
                                                     unsigned long long* __restrict__ parts,
                                                     unsigned* __restrict__ cnt) {
    __shared__ int sP[NSEG][TC + 1], sN[NSEG][TC + 1];
    __shared__ int sCP[NSEG][TC + 1], sCN[NSEG][TC + 1];

    if (blockIdx.x == 0) {             // re-armed every launch (stream-ordered => race-free)
        if (threadIdx.x < 64) parts[threadIdx.x] = 0ull;   // 8 batches x 8 u64 slots
        if (threadIdx.x == 64) *cnt = 0u;
    }

    int blk = blockIdx.x;              // B * 16 tiles * RC = 1024
    int b   = blk >> 7;
    int rem = blk & 127;
    int jt  = rem >> 3;
    int rc  = rem & 7;
    int tid = threadIdx.x;
    int tx  = tid & (TC - 1);
    int ty  = tid >> 5;                // 0..15
    int j   = jt * TC + tx;
    int i0  = rc * CH + ty * LL;

    const float* m = ytrue + ((size_t)b * C + SEL) * H * W + j;
    int gfp[LL], gfn[LL];
    int pp = BIGI, pn = BIGI;
    #pragma unroll
    for (int r = 0; r < LL; ++r) {     // local forward scan, both polarities
        bool fg = (m[(size_t)(i0 + r) * W] != 0.0f);
        int vp = fg ? BIGI : 0;
        int vn = fg ? 0 : BIGI;
        vp = min(vp, pp + 1); gfp[r] = vp; pp = vp;
        vn = min(vn, pn + 1); gfn[r] = vn; pn = vn;
    }
    sP[ty][tx] = pp - ty * LL;         // prefix-min operand
    sN[ty][tx] = pn - ty * LL;
    __syncthreads();

    int col = tid >> 4, seg = tid & 15;    // transposed view: 32 cols x 16 segs
    int wp = sP[seg][col], wn = sN[seg][col];
    #pragma unroll
    for (int d = 1; d < NSEG; d <<= 1) {   // prefix-min over segments
        int a1 = __shfl_up(wp, d, 16);
        int a2 = __shfl_up(wn, d, 16);
        if (seg >= d) { wp = min(wp, a1); wn = min(wn, a2); }
    }
    if (seg < NSEG - 1) {
        sCP[seg + 1][col] = seg * LL + wp;
        sCN[seg + 1][col] = seg * LL + wn;
    } else {
        int jj = jt * TC + col;
        sumsD[((size_t)(b * RC + rc)) * W + jj] =
            (unsigned)(seg * LL + wp) | ((unsigned)(seg * LL + wn) << 16);
    }
    if (seg == 0) { sCP[0][col] = BIGI; sCN[0][col] = BIGI; }
    __syncthreads();

    int cp = sCP[ty][tx], cn = sCN[ty][tx];
    int lbp = 1 << 20, lbn = 1 << 20;
    #pragma unroll
    for (int r = 0; r < LL; ++r) {     // forward fix + local backward summary
        int vp = min(gfp[r], cp + 1 + r); gfp[r] = vp; lbp = min(lbp, vp + r);
        int vn = min(gfn[r], cn + 1 + r); gfn[r] = vn; lbn = min(lbn, vn + r);
    }
    sP[ty][tx] = lbp + ty * LL;        // suffix-min operand
    sN[ty][tx] = lbn + ty * LL;
    __syncthreads();

    int w2p = sP[seg][col], w2n = sN[seg][col];
    #pragma unroll
    for (int d = 1; d < NSEG; d <<= 1) {   // suffix-min over segments
        int a1 = __shfl_down(w2p, d, 16);
        int a2 = __shfl_down(w2n, d, 16);
        if (seg + d < NSEG) { w2p = min(w2p, a1); w2n = min(w2n, a2); }
    }
    if (seg > 0) {
        sCP[seg - 1][col] = w2p - seg * LL;
        sCN[seg - 1][col] = w2n - seg * LL;
    } else {
        int jj = jt * TC + col;
        sumsU[((size_t)(b * RC + rc)) * W + jj] =
            (unsigned)w2p | ((unsigned)w2n << 16);
    }
    if (seg == NSEG - 1) { sCP[NSEG - 1][col] = BIGI; sCN[NSEG - 1][col] = BIGI; }
    __syncthreads();

    int pbp = sCP[ty][tx], pbn = sCN[ty][tx];
    unsigned short g4[LL];
    #pragma unroll
    for (int r = LL - 1; r >= 0; --r) { // local backward pass
        int vp = min(gfp[r], pbp + 1); pbp = vp;
        int vn = min(gfn[r], pbn + 1); pbn = vn;
        int fg = (vn == 0) ? 1 : 0;    // exactly one of vp,vn is 0
        int g2 = vp + vn;              // the nonzero one
        g4[r] = (unsigned short)((g2 << 1) | fg);
    }
    ushort4 pk; pk.x = g4[0]; pk.y = g4[1]; pk.z = g4[2]; pk.w = g4[3];
    *(ushort4*)(gpkT + (((size_t)b * (H / 4) + (i0 >> 2)) * W + j) * 4) = pk;   // coalesced 8B store
}

// ---------------- fused row EDT + fast sigmoid + deterministic integer-atomic finale ----------
// parts[b*8+k]: 0=A(fixed-pt u64 sum), 1=Bv, 2=max d2pos, 3=max d2neg. Integer atomics are
// order-independent => deterministic. No fences: plain device-scope atomics only.
__global__ __launch_bounds__(512) void row_fused(const unsigned short* __restrict__ gpkT,
                                                 const unsigned* __restrict__ sumsD,
                                                 const unsigned* __restrict__ sumsU,
                                                 const float* __restrict__ ypred,
                                                 unsigned long long* __restrict__ parts,
                                                 unsigned* __restrict__ cnt,
                                                 float* __restrict__ out) {
    __shared__ float s1[G][W];
    __shared__ float sw[4][8];
    __shared__ int lastFlag;

    int blk = blockIdx.x;                 // NRU = 512
    int b = blk >> 6;
    int g = blk & 63;
    int i0 = g * G;
    int rc = i0 >> 6;                     // chunk of these G rows (CH=64, G|CH)
    int tid = threadIdx.x;
    int j = tid;

    // inter-chunk carries from summaries (uniform branches; L2-resident)
    const unsigned* sd = sumsD + (size_t)b * RC * W + j;
    const unsigned* su = sumsU + (size_t)b * RC * W + j;
    int Ap = CINF, An = CINF, Bp = CINF, Bn = CINF;
    #pragma unroll
    for (int q = 0; q < RC; ++q) {
        if (q < rc) {
            unsigned dv = sd[(size_t)q * W];
            int e = q * CH + CH - 1;
            Ap = min(Ap, (int)(dv & 0xFFFFu) - e);
            An = min(An, (int)(dv >> 16) - e);
        } else if (q > rc) {
            unsigned uv = su[(size_t)q * W];
            int s0 = q * CH;
            Bp = min(Bp, (int)(uv & 0xFFFFu) + s0);
            Bn = min(Bn, (int)(uv >> 16) + s0);
        }
    }

    float svr[G];
    #pragma unroll
    for (int h = 0; h < G; h += 4) {
        const ushort4 v4 = *(const ushort4*)(gpkT + (((size_t)b * (H / 4) + ((i0 + h) >> 2)) * W + j) * 4);
        unsigned short vv[4] = { v4.x, v4.y, v4.z, v4.w };
        #pragma unroll
        for (int r = 0; r < 4; ++r) {
            int ii = i0 + h + r;
            unsigned v = vv[r];
            int fg = v & 1;
            int gv = v >> 1;
            int gp = fg ? gv : 0;
            int gn = fg ? 0 : gv;
            gp = min(gp, min(Ap + ii, Bp - ii));   // cross-chunk fix (exact)
            gn = min(gn, min(An + ii, Bn - ii));
            int gg = gp + gn;                      // the nonzero one
            float sv = (float)(gg * gg);
            sv = fg ? sv : -sv;
            svr[h + r] = sv;
            s1[h + r][j] = sv;
        }
    }

    // prefetch ypred into registers (coalesced; latency hides under scan)
    float yv[G][C];
    #pragma unroll
    for (int r = 0; r < G; ++r) {
        const float* yp = ypred + ((size_t)b * C * H + i0 + r) * W + j;
        #pragma unroll
        for (int cc = 0; cc < C; ++cc) yv[r][cc] = yp[(size_t)cc * H * W];
    }
    __syncthreads();

    int jl1 = (j >= 1) ? j - 1 : j, jr1 = (j < W - 1) ? j + 1 : j;
    int jl2 = (j >= 2) ? j - 2 : j, jr2 = (j < W - 2) ? j + 2 : j;

    float mxp = 0.f, mxn = 0.f, A = 0.f, Bv = 0.f;
    #pragma unroll
    for (int r = 0; r < G; ++r) {
        float sv = svr[r];
        bool fg = (sv > 0.f);
        float sgn = fg ? 1.f : -1.f;
        float bq = fabsf(sv);
        // peeled radii 1,2: branch-free (clamped candidate >= own value -> safe)
        float u1 = s1[r][jl1], u2 = s1[r][jr1], u3 = s1[r][jl2], u4 = s1[r][jr2];
        bq = fminf(bq, fmaxf(u1 * sgn, 0.f) + 1.f);
        bq = fminf(bq, fmaxf(u2 * sgn, 0.f) + 1.f);
        bq = fminf(bq, fmaxf(u3 * sgn, 0.f) + 4.f);
        bq = fminf(bq, fmaxf(u4 * sgn, 0.f) + 4.f);
        float r2 = 9.f, drr = 7.f;            // rr=3: r2=9, then +7,+9,...
        for (int rr = 3; rr < W; ++rr) {      // exact tail (rare)
            if (r2 >= bq) break;              // unvisited candidates >= r2 -> exact
            int jl = j - rr, jr = j + rr;
            if (jl >= 0) { float u = s1[r][jl]; bq = fminf(bq, fmaxf(u * sgn, 0.f) + r2); }
            if (jr < W)  { float u = s1[r][jr]; bq = fminf(bq, fmaxf(u * sgn, 0.f) + r2); }
            r2 += drr; drr += 2.f;
        }
        float d = __builtin_amdgcn_sqrtf(bq);
        bool bnd = fg && (bq == 1.0f);        // inner 4-boundary <=> d2pos == 1

        // fast sigmoid: rcp(1 + exp2(-x*log2e))
        float s = __builtin_amdgcn_rcpf(1.0f + __builtin_amdgcn_exp2f(-yv[r][0] * LOG2E))
                + __builtin_amdgcn_rcpf(1.0f + __builtin_amdgcn_exp2f(-yv[r][1] * LOG2E))
                + __builtin_amdgcn_rcpf(1.0f + __builtin_amdgcn_exp2f(-yv[r][2] * LOG2E))
                + __builtin_amdgcn_rcpf(1.0f + __builtin_amdgcn_exp2f(-yv[r][3] * LOG2E));
        float se = bnd ? 0.f : s;
        mxp = fmaxf(mxp, fg ? bq : 0.f);
        mxn = fmaxf(mxn, fg ? 0.f : bq);
        A  += fg ? se * d : 0.f;
        Bv += fg ? 0.f : se * d;
    }

    for (int off = 32; off >= 1; off >>= 1) {
        mxp = fmaxf(mxp, __shfl_down(mxp, off));
        mxn = fmaxf(mxn, __shfl_down(mxn, off));
        A  += __shfl_down(A, off);
        Bv += __shfl_down(Bv, off);
    }
    int wave = tid >> 6, lane = tid & 63;
    if (lane == 0) { sw[0][wave] = mxp; sw[1][wave] = mxn; sw[2][wave] = A; sw[3][wave] = Bv; }
    __syncthreads();
    if (tid == 0) {
        float a0 = sw[0][0], a1 = sw[1][0], a2 = sw[2][0], a3 = sw[3][0];
        #pragma unroll
        for (int w = 1; w < 8; ++w) {
            a0 = fmaxf(a0, sw[0][w]); a1 = fmaxf(a1, sw[1][w]);
            a2 += sw[2][w]; a3 += sw[3][w];
        }
        unsigned long long* Pb = parts + (size_t)b * 8;
        atomicAdd(Pb + 0, (unsigned long long)(a2 * SCALE_F + 0.5f));   // fixed-point: exact-order-free
        atomicAdd(Pb + 1, (unsigned long long)(a3 * SCALE_F + 0.5f));
        atomicMax(Pb + 2, (unsigned long long)(unsigned)a0);            // d2 integer-valued
        atomicMax(Pb + 3, (unsigned long long)(unsigned)a1);
        asm volatile("s_waitcnt vmcnt(0)" ::: "memory");                // order partials before cnt (no cache ops)
        unsigned prev = atomicAdd(cnt, 1u);
        lastFlag = (prev == (unsigned)(NRU - 1)) ? 1 : 0;
    }
    __syncthreads();

    // ---------------- last block: read partials at coherent point (RMW-0), finish ----------------
    if (lastFlag) {
        double contrib = 0.0;
        if (tid < 8) {                        // lane = batch
            unsigned long long* Pb = parts + (size_t)tid * 8;
            unsigned long long uA = atomicAdd(Pb + 0, 0ull);
            unsigned long long uB = atomicAdd(Pb + 1, 0ull);
            unsigned long long mp = atomicAdd(Pb + 2, 0ull);
            unsigned long long mn = atomicAdd(Pb + 3, 0ull);
            double pmax = sqrt((double)mp), nmax = sqrt((double)mn);
            double Ar = (double)uA * INV_SCALE;
            double Br = (double)uB * INV_SCALE;
            double invp = (pmax > 0.0) ? 1.0 / pmax : 0.0;
            double invn = (nmax > 0.0) ? 1.0 / nmax : 0.0;
            contrib = (pmax > 0.0) ? (invn * Br - invp * Ar) : 0.0;
        }
        contrib += __shfl_down(contrib, 4);   // fixed-order deterministic reduce over 8 lanes
        contrib += __shfl_down(contrib, 2);
        contrib += __shfl_down(contrib, 1);
        if (tid == 0) out[0] = (float)(contrib / (double)((size_t)B * C * H * W));
    }
}

extern "C" void kernel_launch(void* const* d_in, const int* in_sizes, int n_in,
                              void* d_out, int out_size, void* d_ws, size_t ws_size,
                              hipStream_t stream) {
    const float* ypred = (const float*)d_in[0];
    const float* ytrue = (const float*)d_in[1];
    float* out = (float*)d_out;

    unsigned short* gpkT = (unsigned short*)d_ws;           // NPIX u16, [b][i/4][j][4] = 4 MB
    unsigned* sumsD = (unsigned*)(gpkT + NPIX);             // B*RC*W u32 = 128 KB
    unsigned* sumsU = sumsD + (size_t)B * RC * W;           // B*RC*W u32 = 128 KB
    unsigned long long* parts = (unsigned long long*)(sumsU + (size_t)B * RC * W); // 8x8 u64 (8B-aligned)
    unsigned* cnt = (unsigned*)(parts + 64);                // 1 u32

    col_two_level<<<B * 16 * RC, 512, 0, stream>>>(ytrue, gpkT, sumsD, sumsU, parts, cnt);
    row_fused<<<NRU, 512, 0, stream>>>(gpkT, sumsD, sumsU, ypred, parts, cnt, out);
}

// Round 16
// 24.106 us; speedup vs baseline: 1.0984x; 1.0984x over previous
//
#include <hip/hip_runtime.h>
#include <math.h>

#define B 8
#define C 4
#define H 512
#define W 512
#define SEL 1
#define BIGI 1024       // H + W
#define NPIX (B*H*W)
#define CH 64           // rows per chunk
#define RC 8            // chunks per column
#define TC 32           // columns per block
#define NSEG 16         // segments per chunk
#define LL 4            // rows per thread (CH/NSEG)
#define CINF 3000       // "infinite" carry
#define G 8             // rows per row_fused block
#define NRU (B*H/G)     // 512 row blocks (2 per CU)
#define LOG2E 1.4426950408889634f

// ---------------- local (per-chunk) vertical EDT, both polarities ----------------
// output gpkT layout: [b][i/4][j][4] u16, value = (g<<1)|fg
__global__ __launch_bounds__(512) void col_two_level(const float* __restrict__ ytrue,
                                                     unsigned short* __restrict__ gpkT,
                                                     unsigned* __restrict__ sumsD,
                                                     unsigned* __restrict__ sumsU) {
    __shared__ int sP[NSEG][TC + 1], sN[NSEG][TC + 1];
    __shared__ int sCP[NSEG][TC + 1], sCN[NSEG][TC + 1];

    int blk = blockIdx.x;              // B * 16 tiles * RC = 1024
    int b   = blk >> 7;
    int rem = blk & 127;
    int jt  = rem >> 3;
    int rc  = rem & 7;
    int tid = threadIdx.x;
    int tx  = tid & (TC - 1);
    int ty  = tid >> 5;                // 0..15
    int j   = jt * TC + tx;
    int i0  = rc * CH + ty * LL;

    const float* m = ytrue + ((size_t)b * C + SEL) * H * W + j;
    int gfp[LL], gfn[LL];
    int pp = BIGI, pn = BIGI;
    #pragma unroll
    for (int r = 0; r < LL; ++r) {     // local forward scan, both polarities
        bool fg = (m[(size_t)(i0 + r) * W] != 0.0f);
        int vp = fg ? BIGI : 0;
        int vn = fg ? 0 : BIGI;
        vp = min(vp, pp + 1); gfp[r] = vp; pp = vp;
        vn = min(vn, pn + 1); gfn[r] = vn; pn = vn;
    }
    sP[ty][tx] = pp - ty * LL;         // prefix-min operand
    sN[ty][tx] = pn - ty * LL;
    __syncthreads();

    int col = tid >> 4, seg = tid & 15;    // transposed view: 32 cols x 16 segs
    int wp = sP[seg][col], wn = sN[seg][col];
    #pragma unroll
    for (int d = 1; d < NSEG; d <<= 1) {   // prefix-min over segments
        int a1 = __shfl_up(wp, d, 16);
        int a2 = __shfl_up(wn, d, 16);
        if (seg >= d) { wp = min(wp, a1); wn = min(wn, a2); }
    }
    if (seg < NSEG - 1) {
        sCP[seg + 1][col] = seg * LL + wp;
        sCN[seg + 1][col] = seg * LL + wn;
    } else {
        int jj = jt * TC + col;
        sumsD[((size_t)(b * RC + rc)) * W + jj] =
            (unsigned)(seg * LL + wp) | ((unsigned)(seg * LL + wn) << 16);
    }
    if (seg == 0) { sCP[0][col] = BIGI; sCN[0][col] = BIGI; }
    __syncthreads();

    int cp = sCP[ty][tx], cn = sCN[ty][tx];
    int lbp = 1 << 20, lbn = 1 << 20;
    #pragma unroll
    for (int r = 0; r < LL; ++r) {     // forward fix + local backward summary
        int vp = min(gfp[r], cp + 1 + r); gfp[r] = vp; lbp = min(lbp, vp + r);
        int vn = min(gfn[r], cn + 1 + r); gfn[r] = vn; lbn = min(lbn, vn + r);
    }
    sP[ty][tx] = lbp + ty * LL;        // suffix-min operand
    sN[ty][tx] = lbn + ty * LL;
    __syncthreads();

    int w2p = sP[seg][col], w2n = sN[seg][col];
    #pragma unroll
    for (int d = 1; d < NSEG; d <<= 1) {   // suffix-min over segments
        int a1 = __shfl_down(w2p, d, 16);
        int a2 = __shfl_down(w2n, d, 16);
        if (seg + d < NSEG) { w2p = min(w2p, a1); w2n = min(w2n, a2); }
    }
    if (seg > 0) {
        sCP[seg - 1][col] = w2p - seg * LL;
        sCN[seg - 1][col] = w2n - seg * LL;
    } else {
        int jj = jt * TC + col;
        sumsU[((size_t)(b * RC + rc)) * W + jj] =
            (unsigned)w2p | ((unsigned)w2n << 16);
    }
    if (seg == NSEG - 1) { sCP[NSEG - 1][col] = BIGI; sCN[NSEG - 1][col] = BIGI; }
    __syncthreads();

    int pbp = sCP[ty][tx], pbn = sCN[ty][tx];
    unsigned short g4[LL];
    #pragma unroll
    for (int r = LL - 1; r >= 0; --r) { // local backward pass
        int vp = min(gfp[r], pbp + 1); pbp = vp;
        int vn = min(gfn[r], pbn + 1); pbn = vn;
        int fg = (vn == 0) ? 1 : 0;    // exactly one of vp,vn is 0
        int g2 = vp + vn;              // the nonzero one
        g4[r] = (unsigned short)((g2 << 1) | fg);
    }
    ushort4 pk; pk.x = g4[0]; pk.y = g4[1]; pk.z = g4[2]; pk.w = g4[3];
    *(ushort4*)(gpkT + (((size_t)b * (H / 4) + (i0 >> 2)) * W + j) * 4) = pk;   // coalesced 8B store
}

// ---------------- fused row EDT (8 rows, sign-packed peeled scan) + fast sigmoid + partials -------
__global__ __launch_bounds__(512) void row_fused(const unsigned short* __restrict__ gpkT,
                                                 const unsigned* __restrict__ sumsD,
                                                 const unsigned* __restrict__ sumsU,
                                                 const float* __restrict__ ypred,
                                                 float* __restrict__ rowpart) {
    __shared__ float s1[G][W];
    __shared__ float sw[4][8];

    int blk = blockIdx.x;                 // NRU = 512
    int b = blk >> 6;
    int g = blk & 63;
    int i0 = g * G;
    int rc = i0 >> 6;                     // chunk of these G rows (CH=64, G|CH)
    int j = threadIdx.x;

    // inter-chunk carries from summaries (uniform branches; L2-resident)
    const unsigned* sd = sumsD + (size_t)b * RC * W + j;
    const unsigned* su = sumsU + (size_t)b * RC * W + j;
    int Ap = CINF, An = CINF, Bp = CINF, Bn = CINF;
    #pragma unroll
    for (int q = 0; q < RC; ++q) {
        if (q < rc) {
            unsigned dv = sd[(size_t)q * W];
            int e = q * CH + CH - 1;
            Ap = min(Ap, (int)(dv & 0xFFFFu) - e);
            An = min(An, (int)(dv >> 16) - e);
        } else if (q > rc) {
            unsigned uv = su[(size_t)q * W];
            int s0 = q * CH;
            Bp = min(Bp, (int)(uv & 0xFFFFu) + s0);
            Bn = min(Bn, (int)(uv >> 16) + s0);
        }
    }

    float svr[G];
    #pragma unroll
    for (int h = 0; h < G; h += 4) {
        const ushort4 v4 = *(const ushort4*)(gpkT + (((size_t)b * (H / 4) + ((i0 + h) >> 2)) * W + j) * 4);
        unsigned short vv[4] = { v4.x, v4.y, v4.z, v4.w };
        #pragma unroll
        for (int r = 0; r < 4; ++r) {
            int ii = i0 + h + r;
            unsigned v = vv[r];
            int fg = v & 1;
            int gv = v >> 1;
            int gp = fg ? gv : 0;
            int gn = fg ? 0 : gv;
            gp = min(gp, min(Ap + ii, Bp - ii));   // cross-chunk fix (exact)
            gn = min(gn, min(An + ii, Bn - ii));
            int gg = gp + gn;                      // the nonzero one
            float sv = (float)(gg * gg);
            sv = fg ? sv : -sv;
            svr[h + r] = sv;
            s1[h + r][j] = sv;
        }
    }

    // prefetch ypred into registers (32 coalesced loads; latency hides under scan)
    float yv[G][C];
    #pragma unroll
    for (int r = 0; r < G; ++r) {
        const float* yp = ypred + ((size_t)b * C * H + i0 + r) * W + j;
        #pragma unroll
        for (int cc = 0; cc < C; ++cc) yv[r][cc] = yp[(size_t)cc * H * W];
    }
    __syncthreads();

    int jl1 = (j >= 1) ? j - 1 : j, jr1 = (j < W - 1) ? j + 1 : j;
    int jl2 = (j >= 2) ? j - 2 : j, jr2 = (j < W - 2) ? j + 2 : j;

    float mxp = 0.f, mxn = 0.f, A = 0.f, Bv = 0.f;
    #pragma unroll
    for (int r = 0; r < G; ++r) {
        float sv = svr[r];
        bool fg = (sv > 0.f);
        float sgn = fg ? 1.f : -1.f;
        float bq = fabsf(sv);
        // peeled radii 1,2: branch-free (clamped candidate >= own value -> safe)
        float u1 = s1[r][jl1], u2 = s1[r][jr1], u3 = s1[r][jl2], u4 = s1[r][jr2];
        bq = fminf(bq, fmaxf(u1 * sgn, 0.f) + 1.f);
        bq = fminf(bq, fmaxf(u2 * sgn, 0.f) + 1.f);
        bq = fminf(bq, fmaxf(u3 * sgn, 0.f) + 4.f);
        bq = fminf(bq, fmaxf(u4 * sgn, 0.f) + 4.f);
        float r2 = 9.f, drr = 7.f;            // rr=3: r2=9, then +7,+9,...
        for (int rr = 3; rr < W; ++rr) {      // exact tail (rare)
            if (r2 >= bq) break;              // unvisited candidates >= r2 -> exact
            int jl = j - rr, jr = j + rr;
            if (jl >= 0) { float u = s1[r][jl]; bq = fminf(bq, fmaxf(u * sgn, 0.f) + r2); }
            if (jr < W)  { float u = s1[r][jr]; bq = fminf(bq, fmaxf(u * sgn, 0.f) + r2); }
            r2 += drr; drr += 2.f;
        }
        float d = __builtin_amdgcn_sqrtf(bq);
        bool bnd = fg && (bq == 1.0f);        // inner 4-boundary <=> d2pos == 1

        // fast sigmoid: rcp(1 + exp2(-x*log2e)) -- 4 VALU each
        float s = __builtin_amdgcn_rcpf(1.0f + __builtin_amdgcn_exp2f(-yv[r][0] * LOG2E))
                + __builtin_amdgcn_rcpf(1.0f + __builtin_amdgcn_exp2f(-yv[r][1] * LOG2E))
                + __builtin_amdgcn_rcpf(1.0f + __builtin_amdgcn_exp2f(-yv[r][2] * LOG2E))
                + __builtin_amdgcn_rcpf(1.0f + __builtin_amdgcn_exp2f(-yv[r][3] * LOG2E));
        float se = bnd ? 0.f : s;
        mxp = fmaxf(mxp, fg ? bq : 0.f);
        mxn = fmaxf(mxn, fg ? 0.f : bq);
        A  += fg ? se * d : 0.f;
        Bv += fg ? 0.f : se * d;
    }

    for (int off = 32; off >= 1; off >>= 1) {
        mxp = fmaxf(mxp, __shfl_down(mxp, off));
        mxn = fmaxf(mxn, __shfl_down(mxn, off));
        A  += __shfl_down(A, off);
        Bv += __shfl_down(Bv, off);
    }
    int wave = threadIdx.x >> 6, lane = threadIdx.x & 63;
    if (lane == 0) { sw[0][wave] = mxp; sw[1][wave] = mxn; sw[2][wave] = A; sw[3][wave] = Bv; }
    __syncthreads();
    if (threadIdx.x == 0) {
        float a0 = sw[0][0], a1 = sw[1][0], a2 = sw[2][0], a3 = sw[3][0];
        #pragma unroll
        for (int w = 1; w < 8; ++w) {
            a0 = fmaxf(a0, sw[0][w]); a1 = fmaxf(a1, sw[1][w]);
            a2 += sw[2][w]; a3 += sw[3][w];
        }
        *(float4*)(rowpart + (size_t)blk * 4) = make_float4(a0, a1, a2, a3);
    }
}

// ---------------- per-batch stats + total: one wave per batch (64 groups/batch) ----------------
__global__ __launch_bounds__(512) void batch_final(const float* __restrict__ rowpart,
                                                   float* __restrict__ out) {
    __shared__ double sacc[8];
    int bw = threadIdx.x >> 6;            // wave = batch
    int lane = threadIdx.x & 63;
    const float4* rv = (const float4*)(rowpart + (size_t)bw * 64 * 4);
    float4 e0 = rv[lane];                 // 64 groups per batch, one per lane
    float mxp = e0.x, mxn = e0.y;
    float A = e0.z, Bv = e0.w;
    for (int off = 32; off >= 1; off >>= 1) {
        mxp = fmaxf(mxp, __shfl_down(mxp, off));
        mxn = fmaxf(mxn, __shfl_down(mxn, off));
        A  += __shfl_down(A, off);
        Bv += __shfl_down(Bv, off);
    }
    if (lane == 0) {
        float pmax = sqrtf(mxp), nmax = sqrtf(mxn);
        float invp = (pmax > 0.f) ? 1.0f / pmax : 0.0f;
        float invn = (nmax > 0.f) ? 1.0f / nmax : 0.0f;
        sacc[bw] = (pmax > 0.f) ? (double)(invn * Bv - invp * A) : 0.0;
    }
    __syncthreads();
    if (threadIdx.x == 0) {
        double tt = 0.0;
        #pragma unroll
        for (int q = 0; q < 8; ++q) tt += sacc[q];
        out[0] = (float)(tt / (double)((size_t)B * C * H * W));
    }
}

extern "C" void kernel_launch(void* const* d_in, const int* in_sizes, int n_in,
                              void* d_out, int out_size, void* d_ws, size_t ws_size,
                              hipStream_t stream) {
    const float* ypred = (const float*)d_in[0];
    const float* ytrue = (const float*)d_in[1];
    float* out = (float*)d_out;

    unsigned short* gpkT = (unsigned short*)d_ws;           // NPIX u16, [b][i/4][j][4] = 4 MB
    unsigned* sumsD = (unsigned*)(gpkT + NPIX);             // B*RC*W u32 = 128 KB
    unsigned* sumsU = sumsD + (size_t)B * RC * W;           // B*RC*W u32 = 128 KB
    float* rowpart = (float*)(sumsU + (size_t)B * RC * W);  // NRU*4 f32 = 8 KB

    col_two_level<<<B * 16 * RC, 512, 0, stream>>>(ytrue, gpkT, sumsD, sumsU);
    row_fused<<<NRU, 512, 0, stream>>>(gpkT, sumsD, sumsU, ypred, rowpart);
    batch_final<<<1, 512, 0, stream>>>(rowpart, out);
}